// Round 6
// baseline (242.664 us; speedup 1.0000x reference)
//
#include <hip/hip_runtime.h>

#define BUCKET_BITS 7
#define BUCKET_N    128     // nodes per bucket
#define SEG_CAP     1280    // edge capacity per bucket segment (lambda ~1023, +8 sigma)
#define EPB         4096    // edges per scatter block
#define EPT         16      // edges per thread in scatter
#define OVF_CAP     16384
#define MAXBUCK     1024    // static LDS histogram size (N up to 131k)

// ============ Init: cursors to segment starts, zero accumulators ============
__global__ void k_init(int* __restrict__ cursor, int* __restrict__ ovf_n,
                       float* __restrict__ T1, float* __restrict__ T2,
                       float* __restrict__ cntg, int nbuck, int n_graphs)
{
    const int t = threadIdx.x;
    for (int i = t; i < nbuck; i += 1024) cursor[i * 16] = i * SEG_CAP;
    if (t < n_graphs) { T1[t] = 0.f; T2[t] = 0.f; cntg[t] = 0.f; }
    if (t == 0) *ovf_n = 0;
}

// ============ Deterministic bucket binning: LDS hist + one range-reserve atomic
//              per (block,bucket), then contiguous int2 writes ============
__global__ __launch_bounds__(256) void k_scatter_bin(
    const int* __restrict__ src, const int* __restrict__ dst,
    int* __restrict__ cursor, int2* __restrict__ seg,
    int* __restrict__ ovf_n, int2* __restrict__ ovf,
    int n_edges, int nbuck)
{
    __shared__ int hist[MAXBUCK];
    __shared__ int base[MAXBUCK];
    const int t = threadIdx.x;
    for (int i = t; i < nbuck; i += 256) hist[i] = 0;
    __syncthreads();

    const int e0 = blockIdx.x * EPB;
    int es[EPT], ed[EPT], ep[EPT];
#pragma unroll
    for (int k = 0; k < EPT; ++k) {
        const int e = e0 + k * 256 + t;   // coalesced per k
        if (e < n_edges) {
            ed[k] = dst[e];
            es[k] = src[e];
            ep[k] = atomicAdd(&hist[ed[k] >> BUCKET_BITS], 1);  // LDS atomic
        } else ed[k] = -1;
    }
    __syncthreads();
    for (int b = t; b < nbuck; b += 256) {
        const int h = hist[b];
        base[b] = h ? atomicAdd(&cursor[b * 16], h) : 0;  // one reserve per (block,bucket)
    }
    __syncthreads();
#pragma unroll
    for (int k = 0; k < EPT; ++k) {
        if (ed[k] >= 0) {
            const int b = ed[k] >> BUCKET_BITS;
            const int addr = base[b] + ep[k];
            if (addr < (b + 1) * SEG_CAP) {
                seg[addr] = make_int2(es[k], ed[k]);   // 8B, bucket-contiguous runs
            } else {
                const int op = atomicAdd(ovf_n, 1);    // expected never
                if (op < OVF_CAP) ovf[op] = make_int2(es[k], ed[k]);
            }
        }
    }
}

// ============ Transform1: p1 = x@W1rel, r1 = x@W1root + b1 (64->16) ============
__global__ __launch_bounds__(256) void k_transform1(
    const float* __restrict__ x, const float* __restrict__ Wrel,
    const float* __restrict__ Wroot, const float* __restrict__ bias,
    float* __restrict__ p1, float* __restrict__ r1, int n_nodes)
{
    __shared__ float s_x[64 * 68];
    __shared__ float s_wrT[16 * 68];
    __shared__ float s_woT[16 * 68];
    __shared__ float s_b[16];

    const int t = threadIdx.x;
    for (int i = t; i < 1024; i += 256) {
        const int k = i >> 4, o = i & 15;
        s_wrT[o * 68 + k] = Wrel[i];
        s_woT[o * 68 + k] = Wroot[i];
    }
    if (t < 16) s_b[t] = bias[t];

    const int node0 = blockIdx.x * 64;
    for (int i = t; i < 1024; i += 256) {
        const int r = i >> 4, c = i & 15;
        const int node = node0 + r;
        if (node < n_nodes)
            *(float4*)&s_x[r * 68 + c * 4] =
                *(const float4*)(x + (size_t)node * 64 + c * 4);
    }
    __syncthreads();

    const int o = t & 15, ng = t >> 4;
    float accr[4] = {0.f, 0.f, 0.f, 0.f};
    float acco[4] = {0.f, 0.f, 0.f, 0.f};
#pragma unroll
    for (int k4 = 0; k4 < 16; ++k4) {
        const float4 wr = *(const float4*)&s_wrT[o * 68 + k4 * 4];
        const float4 wo = *(const float4*)&s_woT[o * 68 + k4 * 4];
#pragma unroll
        for (int j = 0; j < 4; ++j) {
            const float4 xv = *(const float4*)&s_x[(ng * 4 + j) * 68 + k4 * 4];
            accr[j] = fmaf(xv.x, wr.x, fmaf(xv.y, wr.y, fmaf(xv.z, wr.z, fmaf(xv.w, wr.w, accr[j]))));
            acco[j] = fmaf(xv.x, wo.x, fmaf(xv.y, wo.y, fmaf(xv.z, wo.z, fmaf(xv.w, wo.w, acco[j]))));
        }
    }
#pragma unroll
    for (int j = 0; j < 4; ++j) {
        const int node = node0 + ng * 4 + j;
        if (node < n_nodes) {
            p1[(size_t)node * 16 + o] = accr[j];
            r1[(size_t)node * 16 + o] = acco[j] + s_b[o];
        }
    }
}

// ============ Aggregate (one block per bucket): LDS tile accumulation,
//              then fused relu + folded-W2 dots + T2/count bins ============
__global__ __launch_bounds__(256) void k_aggregate(
    const float* __restrict__ p1, const float* __restrict__ r1,
    const int2* __restrict__ seg, const int* __restrict__ cursor,
    const int* __restrict__ ovf_n, const int2* __restrict__ ovf,
    const int* __restrict__ batch,
    const float* __restrict__ W2rel, const float* __restrict__ W2root,
    const float* __restrict__ Wlin,
    float* __restrict__ s_out, float* __restrict__ T2, float* __restrict__ cntg,
    int n_nodes)
{
    __shared__ float agg[BUCKET_N * 17];   // pad 16->17: spread banks for strided atomics
    __shared__ float s_w2r[16], s_w2o[16];
    __shared__ float sT2[64], scnt[64];

    const int t = threadIdx.x;
    const int b = blockIdx.x;
    for (int i = t; i < BUCKET_N * 17; i += 256) agg[i] = 0.f;
    if (t < 16) {   // fold W2 through linear head
        float ar = 0.f, ao = 0.f;
#pragma unroll
        for (int o = 0; o < 16; ++o) {
            const float wl = Wlin[o];
            ar = fmaf(W2rel[t * 16 + o], wl, ar);
            ao = fmaf(W2root[t * 16 + o], wl, ao);
        }
        s_w2r[t] = ar; s_w2o[t] = ao;
    }
    if (t < 64) { sT2[t] = 0.f; scnt[t] = 0.f; }
    __syncthreads();

    const int bstart = b * SEG_CAP;
    const int count = min(cursor[b * 16] - bstart, SEG_CAP);

    // 4 lanes per edge (q = float4 quarter): 64 edges in flight per iter
    const int q = t & 3, le = t >> 2;
    for (int i = le; i < count; i += 64) {
        const int2 e = seg[bstart + i];
        const int local = e.y & (BUCKET_N - 1);
        const float4 v = *(const float4*)(p1 + (size_t)e.x * 16 + q * 4);
        float* ap = &agg[local * 17 + q * 4];
        atomicAdd(ap + 0, v.x);
        atomicAdd(ap + 1, v.y);
        atomicAdd(ap + 2, v.z);
        atomicAdd(ap + 3, v.w);
    }
    // overflow tail (expected 0)
    const int no = min(*ovf_n, OVF_CAP);
    for (int i = t; i < no; i += 256) {
        const int2 e = ovf[i];
        if ((e.y >> BUCKET_BITS) == b) {
            const int local = e.y & (BUCKET_N - 1);
            for (int f = 0; f < 16; ++f)
                atomicAdd(&agg[local * 17 + f], p1[(size_t)e.x * 16 + f]);
        }
    }
    __syncthreads();

    // epilogue: one thread per node
    const int node = b * BUCKET_N + t;
    if (t < BUCKET_N && node < n_nodes) {
        float ps = 0.f, pu = 0.f;
#pragma unroll
        for (int f = 0; f < 16; ++f) {
            float hv = agg[t * 17 + f] + r1[(size_t)node * 16 + f];
            hv = fmaxf(hv, 0.f);
            ps = fmaf(hv, s_w2r[f], ps);
            pu = fmaf(hv, s_w2o[f], pu);
        }
        s_out[node] = ps;
        const int g = batch[node];
        atomicAdd(&sT2[g], pu);
        atomicAdd(&scnt[g], 1.f);
    }
    __syncthreads();
    if (t < 64) {
        if (sT2[t] != 0.f) unsafeAtomicAdd(&T2[t], sT2[t]);
        if (scnt[t] != 0.f) unsafeAtomicAdd(&cntg[t], scnt[t]);
    }
}

// ============ T1: per edge T1[batch[dst]] += s[src], bucket segments ============
__global__ __launch_bounds__(256) void k_T1(
    const float* __restrict__ s_in, const int2* __restrict__ seg,
    const int* __restrict__ cursor, const int* __restrict__ batch,
    const int* __restrict__ ovf_n, const int2* __restrict__ ovf,
    float* __restrict__ T1, int n_nodes)
{
    __shared__ float bins[64];
    __shared__ int sbatch[BUCKET_N];
    const int t = threadIdx.x;
    const int b = blockIdx.x;
    if (t < 64) bins[t] = 0.f;
    const int node = b * BUCKET_N + t;
    if (t < BUCKET_N) sbatch[t] = (node < n_nodes) ? batch[node] : 0;
    __syncthreads();

    const int bstart = b * SEG_CAP;
    const int count = min(cursor[b * 16] - bstart, SEG_CAP);
    for (int i = t; i < count; i += 256) {
        const int2 e = seg[bstart + i];
        atomicAdd(&bins[sbatch[e.y & (BUCKET_N - 1)]], s_in[e.x]);
    }
    const int no = min(*ovf_n, OVF_CAP);
    for (int i = t; i < no; i += 256) {
        const int2 e = ovf[i];
        if ((e.y >> BUCKET_BITS) == b)
            atomicAdd(&bins[sbatch[e.y & (BUCKET_N - 1)]], s_in[e.x]);
    }
    __syncthreads();
    if (t < 64 && bins[t] != 0.f) unsafeAtomicAdd(&T1[t], bins[t]);
}

// ============ Head: out[g] = (T1+T2)/c + b2.Wlin + blin ============
__global__ void k_finalize(
    const float* __restrict__ T1, const float* __restrict__ T2,
    const float* __restrict__ cntg, const float* __restrict__ b2,
    const float* __restrict__ Wlin, const float* __restrict__ blin,
    float* __restrict__ out, int n_graphs)
{
    const int g = threadIdx.x;
    if (g >= n_graphs) return;
    float cb = 0.f;
#pragma unroll
    for (int o = 0; o < 16; ++o) cb = fmaf(b2[o], Wlin[o], cb);
    const float c = fmaxf(cntg[g], 1.f);
    out[g] = (T1[g] + T2[g]) / c + cb + blin[0];
}

extern "C" void kernel_launch(void* const* d_in, const int* in_sizes, int n_in,
                              void* d_out, int out_size, void* d_ws, size_t ws_size,
                              hipStream_t stream) {
    const float* x       = (const float*)d_in[0];
    const int*   ei      = (const int*)d_in[1];
    const int*   batch   = (const int*)d_in[2];
    const float* W1_rel  = (const float*)d_in[3];
    const float* W1_root = (const float*)d_in[4];
    const float* b1      = (const float*)d_in[5];
    const float* W2_rel  = (const float*)d_in[6];
    const float* W2_root = (const float*)d_in[7];
    const float* b2      = (const float*)d_in[8];
    const float* Wlin    = (const float*)d_in[9];
    const float* blin    = (const float*)d_in[10];
    float* out = (float*)d_out;

    const int N = in_sizes[0] / 64;
    const int E = in_sizes[1] / 2;
    const int G = out_size;
    const int nbuck = (N + BUCKET_N - 1) >> BUCKET_BITS;   // 782 for N=100k (<= MAXBUCK)

    const int* src = ei;
    const int* dst = ei + E;

    // ---- workspace layout, 16B-rounded regions ----
    auto rnd4 = [](size_t v) { return (v + 3) & ~(size_t)3; };
    float* ws = (float*)d_ws;
    size_t off = 0;
    float* p1     = ws + off; off += rnd4((size_t)N * 16);
    float* r1     = ws + off; off += rnd4((size_t)N * 16);
    float* s_buf  = ws + off; off += rnd4((size_t)N);
    int*   cursor = (int*)(ws + off); off += rnd4((size_t)nbuck * 16);
    int2*  seg    = (int2*)(ws + off); off += rnd4((size_t)nbuck * SEG_CAP * 2);
    int2*  ovf    = (int2*)(ws + off); off += rnd4((size_t)OVF_CAP * 2);
    int*   ovf_n  = (int*)(ws + off); off += 4;
    float* T1     = ws + off; off += rnd4((size_t)G);
    float* T2     = ws + off; off += rnd4((size_t)G);
    float* cntg   = ws + off; off += rnd4((size_t)G);

    const int sb = (E + EPB - 1) / EPB;   // scatter blocks
    const int tb = (N + 63) / 64;         // transform blocks

    k_init       <<<1, 1024, 0, stream>>>(cursor, ovf_n, T1, T2, cntg, nbuck, G);
    k_scatter_bin<<<sb, 256, 0, stream>>>(src, dst, cursor, seg, ovf_n, ovf, E, nbuck);
    k_transform1 <<<tb, 256, 0, stream>>>(x, W1_rel, W1_root, b1, p1, r1, N);
    k_aggregate  <<<nbuck, 256, 0, stream>>>(p1, r1, seg, cursor, ovf_n, ovf, batch,
                                             W2_rel, W2_root, Wlin, s_buf, T2, cntg, N);
    k_T1         <<<nbuck, 256, 0, stream>>>(s_buf, seg, cursor, batch, ovf_n, ovf, T1, N);
    k_finalize   <<<1, 64, 0, stream>>>(T1, T2, cntg, b2, Wlin, blin, out, G);
}

// Round 7
// 169.282 us; speedup vs baseline: 1.4335x; 1.4335x over previous
//
#include <hip/hip_runtime.h>

#define BUCKET_BITS 7
#define BUCKET_N    128     // nodes per bucket
#define SEG_CAP     1280    // edge capacity per bucket segment (lambda ~1023, +8 sigma)
#define EPB         4096    // edges per scatter block
#define EPT         16      // edges per thread in scatter
#define OVF_CAP     16384
#define MAXBUCK     1024    // static LDS histogram size (N up to 131k)

// ============ Init: cursors to segment starts, zero accumulators ============
__global__ void k_init(int* __restrict__ cursor, int* __restrict__ ovf_n,
                       float* __restrict__ T1, float* __restrict__ T2,
                       float* __restrict__ cntg, int nbuck, int n_graphs)
{
    const int t = threadIdx.x;
    for (int i = t; i < nbuck; i += 1024) cursor[i * 16] = i * SEG_CAP;
    if (t < n_graphs) { T1[t] = 0.f; T2[t] = 0.f; cntg[t] = 0.f; }
    if (t == 0) *ovf_n = 0;
}

// ============ Deterministic bucket binning: LDS hist + one range-reserve atomic
//              per (block,bucket), then contiguous int2 writes ============
__global__ __launch_bounds__(256) void k_scatter_bin(
    const int* __restrict__ src, const int* __restrict__ dst,
    int* __restrict__ cursor, int2* __restrict__ seg,
    int* __restrict__ ovf_n, int2* __restrict__ ovf,
    int n_edges, int nbuck)
{
    __shared__ int hist[MAXBUCK];
    __shared__ int base[MAXBUCK];
    const int t = threadIdx.x;
    for (int i = t; i < nbuck; i += 256) hist[i] = 0;
    __syncthreads();

    const int e0 = blockIdx.x * EPB;
    int es[EPT], ed[EPT], ep[EPT];
#pragma unroll
    for (int k = 0; k < EPT; ++k) {
        const int e = e0 + k * 256 + t;   // coalesced per k
        if (e < n_edges) {
            ed[k] = dst[e];
            es[k] = src[e];
            ep[k] = atomicAdd(&hist[ed[k] >> BUCKET_BITS], 1);  // LDS atomic
        } else ed[k] = -1;
    }
    __syncthreads();
    for (int b = t; b < nbuck; b += 256) {
        const int h = hist[b];
        base[b] = h ? atomicAdd(&cursor[b * 16], h) : 0;  // one reserve per (block,bucket)
    }
    __syncthreads();
#pragma unroll
    for (int k = 0; k < EPT; ++k) {
        if (ed[k] >= 0) {
            const int b = ed[k] >> BUCKET_BITS;
            const int addr = base[b] + ep[k];
            if (addr < (b + 1) * SEG_CAP) {
                seg[addr] = make_int2(es[k], ed[k]);   // 8B, bucket-contiguous runs
            } else {
                const int op = atomicAdd(ovf_n, 1);    // expected never
                if (op < OVF_CAP) ovf[op] = make_int2(es[k], ed[k]);
            }
        }
    }
}

// ============ Transform1: p1 = x@W1rel, r1 = x@W1root + b1 (64->16) ============
__global__ __launch_bounds__(256) void k_transform1(
    const float* __restrict__ x, const float* __restrict__ Wrel,
    const float* __restrict__ Wroot, const float* __restrict__ bias,
    float* __restrict__ p1, float* __restrict__ r1, int n_nodes)
{
    __shared__ float s_x[64 * 68];
    __shared__ float s_wrT[16 * 68];
    __shared__ float s_woT[16 * 68];
    __shared__ float s_b[16];

    const int t = threadIdx.x;
    for (int i = t; i < 1024; i += 256) {
        const int k = i >> 4, o = i & 15;
        s_wrT[o * 68 + k] = Wrel[i];
        s_woT[o * 68 + k] = Wroot[i];
    }
    if (t < 16) s_b[t] = bias[t];

    const int node0 = blockIdx.x * 64;
    for (int i = t; i < 1024; i += 256) {
        const int r = i >> 4, c = i & 15;
        const int node = node0 + r;
        if (node < n_nodes)
            *(float4*)&s_x[r * 68 + c * 4] =
                *(const float4*)(x + (size_t)node * 64 + c * 4);
    }
    __syncthreads();

    const int o = t & 15, ng = t >> 4;
    float accr[4] = {0.f, 0.f, 0.f, 0.f};
    float acco[4] = {0.f, 0.f, 0.f, 0.f};
#pragma unroll
    for (int k4 = 0; k4 < 16; ++k4) {
        const float4 wr = *(const float4*)&s_wrT[o * 68 + k4 * 4];
        const float4 wo = *(const float4*)&s_woT[o * 68 + k4 * 4];
#pragma unroll
        for (int j = 0; j < 4; ++j) {
            const float4 xv = *(const float4*)&s_x[(ng * 4 + j) * 68 + k4 * 4];
            accr[j] = fmaf(xv.x, wr.x, fmaf(xv.y, wr.y, fmaf(xv.z, wr.z, fmaf(xv.w, wr.w, accr[j]))));
            acco[j] = fmaf(xv.x, wo.x, fmaf(xv.y, wo.y, fmaf(xv.z, wo.z, fmaf(xv.w, wo.w, acco[j]))));
        }
    }
#pragma unroll
    for (int j = 0; j < 4; ++j) {
        const int node = node0 + ng * 4 + j;
        if (node < n_nodes) {
            p1[(size_t)node * 16 + o] = accr[j];
            r1[(size_t)node * 16 + o] = acco[j] + s_b[o];
        }
    }
}

// ============ Aggregate v2: counting-sort bucket edges by local dst (2 LDS atomics
//              per edge), then per-node REGISTER accumulation (2 threads/node,
//              zero atomics), fused relu + folded-W2 epilogue. Persists sorted
//              adjacency for k_T1. ============
__global__ __launch_bounds__(256) void k_aggregate(
    const float* __restrict__ p1, const float* __restrict__ r1,
    const int2* __restrict__ seg, const int* __restrict__ cursor,
    const int* __restrict__ ovf_n, const int2* __restrict__ ovf,
    const int* __restrict__ batch,
    const float* __restrict__ W2rel, const float* __restrict__ W2root,
    const float* __restrict__ Wlin,
    float* __restrict__ s_out, float* __restrict__ T2, float* __restrict__ cntg,
    int* __restrict__ g_sorted, int* __restrict__ g_beg, int* __restrict__ g_cnt,
    int n_nodes)
{
    __shared__ int s_src[SEG_CAP];
    __shared__ int hist[BUCKET_N];
    __shared__ int iscan[BUCKET_N];
    __shared__ int cur[BUCKET_N];
    __shared__ float s_w2r[16], s_w2o[16];
    __shared__ float sT2[64], scnt[64];
    __shared__ int s_no;

    const int t = threadIdx.x, b = blockIdx.x;
    if (t < BUCKET_N) hist[t] = 0;
    if (t < 16) {   // fold W2 through linear head
        float ar = 0.f, ao = 0.f;
#pragma unroll
        for (int o = 0; o < 16; ++o) {
            const float wl = Wlin[o];
            ar = fmaf(W2rel[t * 16 + o], wl, ar);
            ao = fmaf(W2root[t * 16 + o], wl, ao);
        }
        s_w2r[t] = ar; s_w2o[t] = ao;
    }
    if (t < 64) { sT2[t] = 0.f; scnt[t] = 0.f; }
    if (t == 0) s_no = min(*ovf_n, OVF_CAP);
    __syncthreads();

    const int bstart = b * SEG_CAP;
    const int count = min(cursor[b * 16] - bstart, SEG_CAP);

    // pass 1: histogram by local dst (1 LDS atomic/edge)
    for (int i = t; i < count; i += 256)
        atomicAdd(&hist[seg[bstart + i].y & (BUCKET_N - 1)], 1);
    __syncthreads();
    // inclusive scan over 128 bins
    if (t < BUCKET_N) iscan[t] = hist[t];
    __syncthreads();
    for (int off = 1; off < BUCKET_N; off <<= 1) {
        int x = 0;
        if (t < BUCKET_N) { x = iscan[t]; if (t >= off) x += iscan[t - off]; }
        __syncthreads();
        if (t < BUCKET_N) iscan[t] = x;
        __syncthreads();
    }
    if (t < BUCKET_N) cur[t] = iscan[t] - hist[t];   // exclusive offsets
    __syncthreads();
    // pass 2: place src into sorted order (1 LDS atomic/edge)
    for (int i = t; i < count; i += 256) {
        const int2 e = seg[bstart + i];
        const int l = e.y & (BUCKET_N - 1);
        s_src[atomicAdd(&cur[l], 1)] = e.x;
    }
    __syncthreads();

    // persist sorted adjacency (coalesced) for k_T1
    for (int i = t; i < count; i += 256) g_sorted[bstart + i] = s_src[i];
    if (t < BUCKET_N) {
        const int nodew = b * BUCKET_N + t;
        if (nodew < n_nodes) {
            g_beg[nodew] = bstart + iscan[t] - hist[t];
            g_cnt[nodew] = hist[t];
        }
    }

    // register accumulation: 2 threads per node, 8 floats (2 float4) each
    const int nl = t >> 1, half = t & 1;
    const int node = b * BUCKET_N + nl;
    if (node < n_nodes) {
        const int end = iscan[nl];
        const int beg = end - hist[nl];
        float4 acc0 = make_float4(0.f, 0.f, 0.f, 0.f);
        float4 acc1 = make_float4(0.f, 0.f, 0.f, 0.f);
        int j = beg;
        for (; j + 2 <= end; j += 2) {     // 4 independent float4 loads in flight
            const int s0 = s_src[j], s1 = s_src[j + 1];
            const float4* q0 = (const float4*)(p1 + (size_t)s0 * 16 + half * 8);
            const float4* q1 = (const float4*)(p1 + (size_t)s1 * 16 + half * 8);
            const float4 a0 = q0[0], a1 = q0[1], b0 = q1[0], b1 = q1[1];
            acc0.x += a0.x + b0.x; acc0.y += a0.y + b0.y;
            acc0.z += a0.z + b0.z; acc0.w += a0.w + b0.w;
            acc1.x += a1.x + b1.x; acc1.y += a1.y + b1.y;
            acc1.z += a1.z + b1.z; acc1.w += a1.w + b1.w;
        }
        if (j < end) {
            const int s0 = s_src[j];
            const float4* q0 = (const float4*)(p1 + (size_t)s0 * 16 + half * 8);
            const float4 a0 = q0[0], a1 = q0[1];
            acc0.x += a0.x; acc0.y += a0.y; acc0.z += a0.z; acc0.w += a0.w;
            acc1.x += a1.x; acc1.y += a1.y; acc1.z += a1.z; acc1.w += a1.w;
        }
        // overflow tail (expected 0)
        for (int ov = 0; ov < s_no; ++ov) {
            const int2 e = ovf[ov];
            if (e.y == node) {
                const float4* q0 = (const float4*)(p1 + (size_t)e.x * 16 + half * 8);
                const float4 a0 = q0[0], a1 = q0[1];
                acc0.x += a0.x; acc0.y += a0.y; acc0.z += a0.z; acc0.w += a0.w;
                acc1.x += a1.x; acc1.y += a1.y; acc1.z += a1.z; acc1.w += a1.w;
            }
        }
        // epilogue: h = acc + r1, relu, folded-W2 dots; combine halves via shfl
        const float4 rA = *(const float4*)(r1 + (size_t)node * 16 + half * 8);
        const float4 rB = *(const float4*)(r1 + (size_t)node * 16 + half * 8 + 4);
        float4 h0, h1;
        h0.x = fmaxf(acc0.x + rA.x, 0.f); h0.y = fmaxf(acc0.y + rA.y, 0.f);
        h0.z = fmaxf(acc0.z + rA.z, 0.f); h0.w = fmaxf(acc0.w + rA.w, 0.f);
        h1.x = fmaxf(acc1.x + rB.x, 0.f); h1.y = fmaxf(acc1.y + rB.y, 0.f);
        h1.z = fmaxf(acc1.z + rB.z, 0.f); h1.w = fmaxf(acc1.w + rB.w, 0.f);
        const float4 w0r = *(const float4*)&s_w2r[half * 8];
        const float4 w1r = *(const float4*)&s_w2r[half * 8 + 4];
        const float4 w0o = *(const float4*)&s_w2o[half * 8];
        const float4 w1o = *(const float4*)&s_w2o[half * 8 + 4];
        float ps = h0.x * w0r.x + h0.y * w0r.y + h0.z * w0r.z + h0.w * w0r.w
                 + h1.x * w1r.x + h1.y * w1r.y + h1.z * w1r.z + h1.w * w1r.w;
        float pu = h0.x * w0o.x + h0.y * w0o.y + h0.z * w0o.z + h0.w * w0o.w
                 + h1.x * w1o.x + h1.y * w1o.y + h1.z * w1o.z + h1.w * w1o.w;
        ps += __shfl_xor(ps, 1);
        pu += __shfl_xor(pu, 1);
        if (half == 0) {
            s_out[node] = ps;
            const int g = batch[node];
            atomicAdd(&sT2[g], pu);
            atomicAdd(&scnt[g], 1.f);
        }
    }
    __syncthreads();
    if (t < 64) {
        if (sT2[t] != 0.f) unsafeAtomicAdd(&T2[t], sT2[t]);
        if (scnt[t] != 0.f) unsafeAtomicAdd(&cntg[t], scnt[t]);
    }
}

// ============ T1 v2: per-node run over sorted adjacency, 1 LDS atomic/node ============
__global__ __launch_bounds__(256) void k_T1(
    const float* __restrict__ s_in, const int* __restrict__ g_sorted,
    const int* __restrict__ g_beg, const int* __restrict__ g_cnt,
    const int* __restrict__ batch,
    const int* __restrict__ ovf_n, const int2* __restrict__ ovf,
    float* __restrict__ T1, int n_nodes)
{
    __shared__ float bins[64];
    const int t = threadIdx.x;
    if (t < 64) bins[t] = 0.f;
    __syncthreads();

    const int node = blockIdx.x * 256 + t;
    if (node < n_nodes) {
        const int beg = g_beg[node], c = g_cnt[node];
        float acc = 0.f;
        int j = 0;
        for (; j + 4 <= c; j += 4) {
            const int a = g_sorted[beg + j],     b2 = g_sorted[beg + j + 1];
            const int cc = g_sorted[beg + j + 2], d = g_sorted[beg + j + 3];
            acc += s_in[a] + s_in[b2] + s_in[cc] + s_in[d];
        }
        for (; j < c; ++j) acc += s_in[g_sorted[beg + j]];
        if (acc != 0.f) atomicAdd(&bins[batch[node]], acc);
    }
    __syncthreads();
    if (t < 64 && bins[t] != 0.f) unsafeAtomicAdd(&T1[t], bins[t]);

    if (blockIdx.x == 0) {   // overflow tail (expected 0)
        const int n = min(*ovf_n, OVF_CAP);
        for (int i = t; i < n; i += 256)
            unsafeAtomicAdd(&T1[batch[ovf[i].y]], s_in[ovf[i].x]);
    }
}

// ============ Head: out[g] = (T1+T2)/c + b2.Wlin + blin ============
__global__ void k_finalize(
    const float* __restrict__ T1, const float* __restrict__ T2,
    const float* __restrict__ cntg, const float* __restrict__ b2,
    const float* __restrict__ Wlin, const float* __restrict__ blin,
    float* __restrict__ out, int n_graphs)
{
    const int g = threadIdx.x;
    if (g >= n_graphs) return;
    float cb = 0.f;
#pragma unroll
    for (int o = 0; o < 16; ++o) cb = fmaf(b2[o], Wlin[o], cb);
    const float c = fmaxf(cntg[g], 1.f);
    out[g] = (T1[g] + T2[g]) / c + cb + blin[0];
}

extern "C" void kernel_launch(void* const* d_in, const int* in_sizes, int n_in,
                              void* d_out, int out_size, void* d_ws, size_t ws_size,
                              hipStream_t stream) {
    const float* x       = (const float*)d_in[0];
    const int*   ei      = (const int*)d_in[1];
    const int*   batch   = (const int*)d_in[2];
    const float* W1_rel  = (const float*)d_in[3];
    const float* W1_root = (const float*)d_in[4];
    const float* b1      = (const float*)d_in[5];
    const float* W2_rel  = (const float*)d_in[6];
    const float* W2_root = (const float*)d_in[7];
    const float* b2      = (const float*)d_in[8];
    const float* Wlin    = (const float*)d_in[9];
    const float* blin    = (const float*)d_in[10];
    float* out = (float*)d_out;

    const int N = in_sizes[0] / 64;
    const int E = in_sizes[1] / 2;
    const int G = out_size;
    const int nbuck = (N + BUCKET_N - 1) >> BUCKET_BITS;   // 782 for N=100k

    const int* src = ei;
    const int* dst = ei + E;

    // ---- workspace layout, 16B-rounded regions ----
    auto rnd4 = [](size_t v) { return (v + 3) & ~(size_t)3; };
    float* ws = (float*)d_ws;
    size_t off = 0;
    float* p1       = ws + off; off += rnd4((size_t)N * 16);
    float* r1       = ws + off; off += rnd4((size_t)N * 16);
    float* s_buf    = ws + off; off += rnd4((size_t)N);
    int*   cursor   = (int*)(ws + off); off += rnd4((size_t)nbuck * 16);
    int2*  seg      = (int2*)(ws + off); off += rnd4((size_t)nbuck * SEG_CAP * 2);
    int*   g_sorted = (int*)(ws + off); off += rnd4((size_t)nbuck * SEG_CAP);
    int*   g_beg    = (int*)(ws + off); off += rnd4((size_t)N);
    int*   g_cnt    = (int*)(ws + off); off += rnd4((size_t)N);
    int2*  ovf      = (int2*)(ws + off); off += rnd4((size_t)OVF_CAP * 2);
    int*   ovf_n    = (int*)(ws + off); off += 4;
    float* T1       = ws + off; off += rnd4((size_t)G);
    float* T2       = ws + off; off += rnd4((size_t)G);
    float* cntg     = ws + off; off += rnd4((size_t)G);

    const int sb = (E + EPB - 1) / EPB;    // scatter blocks
    const int tb = (N + 63) / 64;          // transform blocks
    const int ab = (N + 255) / 256;        // T1 blocks

    k_init       <<<1, 1024, 0, stream>>>(cursor, ovf_n, T1, T2, cntg, nbuck, G);
    k_scatter_bin<<<sb, 256, 0, stream>>>(src, dst, cursor, seg, ovf_n, ovf, E, nbuck);
    k_transform1 <<<tb, 256, 0, stream>>>(x, W1_rel, W1_root, b1, p1, r1, N);
    k_aggregate  <<<nbuck, 256, 0, stream>>>(p1, r1, seg, cursor, ovf_n, ovf, batch,
                                             W2_rel, W2_root, Wlin, s_buf, T2, cntg,
                                             g_sorted, g_beg, g_cnt, N);
    k_T1         <<<ab, 256, 0, stream>>>(s_buf, g_sorted, g_beg, g_cnt, batch,
                                          ovf_n, ovf, T1, N);
    k_finalize   <<<1, 64, 0, stream>>>(T1, T2, cntg, b2, Wlin, blin, out, G);
}